// Round 7
// baseline (220.471 us; speedup 1.0000x reference)
//
#include <hip/hip_runtime.h>
#include <math.h>

// Problem constants (match reference: B,C,W,H,D = 2,256,32,32,32)
#define Bc   2
#define Cc   256
#define Nn   32768            // W*H*D
#define CHc  128              // C/2
#define LN_EPS 1e-5f

// Fused-kernel tiling
#define TN    64              // spatial positions per tile (block)
#define TPB   512             // threads per block (8 waves)
#define NQ    16              // n-quads per tile (TN/4)
#define CG    32              // channel groups
#define CPG   8               // channels per group (Cc/CG)
#define GRIDX (Nn / TN)       // 512 -> x Bc = 1024 blocks

// Pin a float4 in VGPRs: empty asm ties each component, making the load
// result the ONLY definition — the compiler can no longer rematerialize the
// global load in later phases (R6: VGPR=56 proved it reloaded ~3x from L3).
__device__ __forceinline__ void pin4(float4& v) {
  asm volatile("" : "+v"(v.x), "+v"(v.y), "+v"(v.z), "+v"(v.w));
}

// ---------------------------------------------------------------------------
// Fused kernel: one HBM pass over S and T — tile pinned in registers.
// Thread t: nq = t&15 (n-quad), cg = t>>4 (8 channels). Wave butterfly
// collapses the mask across the wave's 4 cg-subgroups; 8 wave partials in
// LDS. Epilogue rounds ordered so s4 dies after ctx_s, t4 after ctx_t.
// UNSHIFTED softmax (shift-invariant; |mask| <~ 2, fp32-exact; absmax 0.0
// verified R4-R6).
// ---------------------------------------------------------------------------
__global__ __launch_bounds__(TPB, 2) void gc_fused(
    const float* __restrict__ S, const float* __restrict__ T,
    const float* __restrict__ wms, const float* __restrict__ bms,
    const float* __restrict__ wmt, const float* __restrict__ bmt,
    float* __restrict__ ctxnum,   // [2][Bc][Cc] raw weighted sums
    float* __restrict__ rowsum,   // [Bc][Cc]
    float* __restrict__ den,      // [2][Bc] softmax denominators
    float* __restrict__ sumsq) {  // [1]
  const int b    = blockIdx.y;
  const int tid  = threadIdx.x;
  const int nq   = tid & (NQ - 1);
  const int cg   = tid >> 4;
  const int wv   = tid >> 6;
  const int lane = tid & 63;
  const int c0   = cg * CPG;
  const int n0   = blockIdx.x * TN + nq * 4;

  __shared__ float4 mredw[2][8][NQ];   // 4 KB   wave-level mask partials
  __shared__ float  cred[Cc * 17];     // 17 KB  reused channel-partial buffer
  __shared__ float  sqred[8];
  __shared__ float  denred[2][NQ];

  const float bS = bms[0];
  const float bT = bmt[0];

  const float* Sp = S + ((size_t)b * Cc + c0) * Nn + n0;
  const float* Tp = T + ((size_t)b * Cc + c0) * Nn + n0;

  // ---- issue all 16 independent tile loads, then PIN them in VGPRs ----
  float4 s4[CPG], t4[CPG];
#pragma unroll
  for (int i = 0; i < CPG; ++i) s4[i] = *(const float4*)(Sp + (size_t)i * Nn);
#pragma unroll
  for (int i = 0; i < CPG; ++i) t4[i] = *(const float4*)(Tp + (size_t)i * Nn);
#pragma unroll
  for (int i = 0; i < CPG; ++i) { pin4(s4[i]); pin4(t4[i]); }

  float wS[CPG], wT[CPG];
#pragma unroll
  for (int i = 0; i < CPG; ++i) { wS[i] = wms[c0 + i]; wT[i] = wmt[c0 + i]; }

  // ---- mask partials ----
  float4 ms = make_float4(0.f, 0.f, 0.f, 0.f);
  float4 mt = make_float4(0.f, 0.f, 0.f, 0.f);
#pragma unroll
  for (int i = 0; i < CPG; ++i) {
    ms.x += wS[i] * s4[i].x; ms.y += wS[i] * s4[i].y;
    ms.z += wS[i] * s4[i].z; ms.w += wS[i] * s4[i].w;
    mt.x += wT[i] * t4[i].x; mt.y += wT[i] * t4[i].y;
    mt.z += wT[i] * t4[i].z; mt.w += wT[i] * t4[i].w;
  }
  // butterfly across the wave's 4 cg-subgroups (lane bits 4,5) — no barrier
#pragma unroll
  for (int m = 16; m <= 32; m <<= 1) {
    ms.x += __shfl_xor(ms.x, m); ms.y += __shfl_xor(ms.y, m);
    ms.z += __shfl_xor(ms.z, m); ms.w += __shfl_xor(ms.w, m);
    mt.x += __shfl_xor(mt.x, m); mt.y += __shfl_xor(mt.y, m);
    mt.z += __shfl_xor(mt.z, m); mt.w += __shfl_xor(mt.w, m);
  }
  if (lane < NQ) { mredw[0][wv][nq] = ms; mredw[1][wv][nq] = mt; }

  // ---- round A (pre-barrier): rowsum partials + sumsq from live s4/t4 ----
  float sq = 0.f;
#pragma unroll
  for (int i = 0; i < CPG; ++i) {
    const float dx = s4[i].x - t4[i].x, dy = s4[i].y - t4[i].y;
    const float dz = s4[i].z - t4[i].z, dw = s4[i].w - t4[i].w;
    cred[(c0 + i) * 17 + nq] = dx + dy + dz + dw;
    sq += dx * dx + dy * dy + dz * dz + dw * dw;
  }
#pragma unroll
  for (int m = 1; m < 64; m <<= 1) sq += __shfl_xor(sq, m);
  if (lane == 0) sqred[wv] = sq;

  __syncthreads();   // B1: mask partials + credA + sqred visible

  // ---- full mask, exp ----
  float4 Ms = make_float4(0.f, 0.f, 0.f, 0.f);
  float4 Mt = make_float4(0.f, 0.f, 0.f, 0.f);
#pragma unroll
  for (int w = 0; w < 8; ++w) {
    const float4 a = mredw[0][w][nq];
    Ms.x += a.x; Ms.y += a.y; Ms.z += a.z; Ms.w += a.w;
    const float4 c = mredw[1][w][nq];
    Mt.x += c.x; Mt.y += c.y; Mt.z += c.z; Mt.w += c.w;
  }
  float4 es, et;
  es.x = __expf(Ms.x + bS); es.y = __expf(Ms.y + bS);
  es.z = __expf(Ms.z + bS); es.w = __expf(Ms.w + bS);
  et.x = __expf(Mt.x + bT); et.y = __expf(Mt.y + bT);
  et.z = __expf(Mt.z + bT); et.w = __expf(Mt.w + bT);

  if (tid < NQ) {  // cg==0 threads: one denominator contribution per nq
    denred[0][tid] = es.x + es.y + es.z + es.w;
    denred[1][tid] = et.x + et.y + et.z + et.w;
  }

  if (tid < Cc) {  // consume credA: rowsum
    float r = 0.f;
#pragma unroll
    for (int k = 0; k < NQ; ++k) r += cred[tid * 17 + k];
    atomicAdd(&rowsum[(size_t)b * Cc + tid], r);
  } else if (tid == Cc) {
    float v = 0.f;
#pragma unroll
    for (int w = 0; w < 8; ++w) v += sqred[w];
    atomicAdd(sumsq, v);
  }
  __syncthreads();   // B2: credA consumed

  // ---- round B: ctx_s partials (s4 dies here) ----
#pragma unroll
  for (int i = 0; i < CPG; ++i)
    cred[(c0 + i) * 17 + nq] =
        s4[i].x * es.x + s4[i].y * es.y + s4[i].z * es.z + s4[i].w * es.w;
  __syncthreads();   // B3
  if (tid < Cc) {
    float a = 0.f;
#pragma unroll
    for (int k = 0; k < NQ; ++k) a += cred[tid * 17 + k];
    atomicAdd(&ctxnum[((size_t)0 * Bc + b) * Cc + tid], a);
  } else if (tid == Cc + 1) {
    float a = 0.f, c = 0.f;
#pragma unroll
    for (int k = 0; k < NQ; ++k) { a += denred[0][k]; c += denred[1][k]; }
    atomicAdd(&den[0 * Bc + b], a);
    atomicAdd(&den[1 * Bc + b], c);
  }
  __syncthreads();   // B4: cred consumed

  // ---- round C: ctx_t partials (t4 dies here) ----
#pragma unroll
  for (int i = 0; i < CPG; ++i)
    cred[(c0 + i) * 17 + nq] =
        t4[i].x * et.x + t4[i].y * et.y + t4[i].z * et.z + t4[i].w * et.w;
  __syncthreads();   // B5
  if (tid < Cc) {
    float c = 0.f;
#pragma unroll
    for (int k = 0; k < NQ; ++k) c += cred[tid * 17 + k];
    atomicAdd(&ctxnum[((size_t)1 * Bc + b) * Cc + tid], c);
  }
}

// ---------------------------------------------------------------------------
// K4a: channel_add MLP per (tt,b). grid 4, block 1024. ctx = ctxnum/den at
// load time. float4 weight loads.
// ---------------------------------------------------------------------------
__global__ __launch_bounds__(1024) void gc_k4a_mlp(
    const float* __restrict__ ctxr, const float* __restrict__ den,
    const float* __restrict__ w1s, const float* __restrict__ b1s,
    const float* __restrict__ gs,  const float* __restrict__ bes,
    const float* __restrict__ w2s, const float* __restrict__ b2s,
    const float* __restrict__ w1t, const float* __restrict__ b1t,
    const float* __restrict__ gt,  const float* __restrict__ bet,
    const float* __restrict__ w2t, const float* __restrict__ b2t,
    float* __restrict__ addv) {
  const int tt  = blockIdx.x >> 1;
  const int b   = blockIdx.x & 1;
  const int tid = threadIdx.x;

  const float* w1 = tt ? w1t : w1s;
  const float* b1 = tt ? b1t : b1s;
  const float* g  = tt ? gt  : gs;
  const float* be = tt ? bet : bes;
  const float* w2 = tt ? w2t : w2s;
  const float* b2 = tt ? b2t : b2s;

  __shared__ float cxs[Cc];
  __shared__ float part[1024];
  __shared__ float hbuf[CHc];
  __shared__ float hr[CHc];
  __shared__ float2 red2[128];
  __shared__ float mu_s, rstd_s;

  if (tid < Cc)
    cxs[tid] = ctxr[((size_t)tt * Bc + b) * Cc + tid] / den[tt * Bc + b];
  __syncthreads();

  // stage 1: h[j] = sum_c ctx[c]*w1[j][c] + b1[j]   (128 j x 8 segments)
  {
    const int j = tid >> 3, s = tid & 7;
    const float* wr = w1 + j * Cc + s * 32;
    const float4* cx4 = (const float4*)(cxs + s * 32);
    float acc = 0.f;
#pragma unroll
    for (int k = 0; k < 8; ++k) {
      const float4 w = *(const float4*)(wr + k * 4);
      const float4 x = cx4[k];
      acc += w.x * x.x + w.y * x.y + w.z * x.z + w.w * x.w;
    }
    part[tid] = acc;
  }
  __syncthreads();
  if (tid < CHc) {
    float h = b1[tid];
#pragma unroll
    for (int q = 0; q < 8; ++q) h += part[tid * 8 + q];
    hbuf[tid] = h;
  }
  __syncthreads();

  // LN stats over 128
  if (tid < CHc) {
    const float v = hbuf[tid];
    red2[tid] = make_float2(v, v * v);
  }
  __syncthreads();
  for (int s = 64; s > 0; s >>= 1) {
    if (tid < s) {
      red2[tid].x += red2[tid + s].x;
      red2[tid].y += red2[tid + s].y;
    }
    __syncthreads();
  }
  if (tid == 0) {
    const float mu = red2[0].x / (float)CHc;
    const float var = red2[0].y / (float)CHc - mu * mu;
    mu_s = mu;
    rstd_s = rsqrtf(var + LN_EPS);
  }
  __syncthreads();
  if (tid < CHc) {
    const float v = (hbuf[tid] - mu_s) * rstd_s * g[tid] + be[tid];
    hr[tid] = v > 0.f ? v : 0.f;
  }
  __syncthreads();

  // stage 3: addv[c] = sum_j hr[j]*w2[c][j] + b2[c]   (256 c x 4 segments)
  {
    const int c = tid >> 2, q = tid & 3;
    const float* wr = w2 + c * CHc + q * 32;
    const float4* h4 = (const float4*)(hr + q * 32);
    float acc = 0.f;
#pragma unroll
    for (int k = 0; k < 8; ++k) {
      const float4 w = *(const float4*)(wr + k * 4);
      const float4 x = h4[k];
      acc += w.x * x.x + w.y * x.y + w.z * x.z + w.w * x.w;
    }
    part[tid] = acc;
  }
  __syncthreads();
  if (tid < Cc) {
    float acc = b2[tid];
#pragma unroll
    for (int q = 0; q < 4; ++q) acc += part[tid * 4 + q];
    addv[((size_t)tt * Bc + b) * Cc + tid] = acc;
  }
}

// ---------------------------------------------------------------------------
// K4b: final scalar. 1 block, 256 thr.
// out = (sumsq + sum_{b,c} [2*delta*rowsum + N*delta^2]) / B
// ---------------------------------------------------------------------------
__global__ __launch_bounds__(256) void gc_k4b_final(
    const float* __restrict__ addv, const float* __restrict__ rowsum,
    const float* __restrict__ sumsq, float* __restrict__ out) {
  const int tid = threadIdx.x;
  __shared__ float red[256];
  float part = 0.f;
  for (int job = tid; job < Bc * Cc; job += 256) {
    const int c = job & (Cc - 1);
    const int b = job >> 8;
    const float delta = addv[((size_t)0 * Bc + b) * Cc + c] -
                        addv[((size_t)1 * Bc + b) * Cc + c];
    part += 2.f * delta * rowsum[(size_t)b * Cc + c] +
            (float)Nn * delta * delta;
  }
  red[tid] = part;
  __syncthreads();
  for (int s = 128; s > 0; s >>= 1) {
    if (tid < s) red[tid] += red[tid + s];
    __syncthreads();
  }
  if (tid == 0) out[0] = (red[0] + sumsq[0]) / (float)Bc;
}

// ---------------------------------------------------------------------------
extern "C" void kernel_launch(void* const* d_in, const int* in_sizes, int n_in,
                              void* d_out, int out_size, void* d_ws,
                              size_t ws_size, hipStream_t stream) {
  const float* S   = (const float*)d_in[0];
  const float* T   = (const float*)d_in[1];
  const float* wms = (const float*)d_in[2];
  const float* bms = (const float*)d_in[3];
  const float* wmt = (const float*)d_in[4];
  const float* bmt = (const float*)d_in[5];
  const float* w1s = (const float*)d_in[6];
  const float* b1s = (const float*)d_in[7];
  const float* gs  = (const float*)d_in[8];
  const float* bes = (const float*)d_in[9];
  const float* w2s = (const float*)d_in[10];
  const float* b2s = (const float*)d_in[11];
  const float* w1t = (const float*)d_in[12];
  const float* b1t = (const float*)d_in[13];
  const float* gt  = (const float*)d_in[14];
  const float* bet = (const float*)d_in[15];
  const float* w2t = (const float*)d_in[16];
  const float* b2t = (const float*)d_in[17];
  float* out = (float*)d_out;

  // ws layout (floats) — accumulators first so one memset zeroes them all.
  float* ws     = (float*)d_ws;
  float* ctxnum = ws;                         // 2*B*C = 1024
  float* rowsum = ctxnum + 2 * Bc * Cc;       // B*C   = 512
  float* den    = rowsum + Bc * Cc;           // 4
  float* sumsq  = den + 4;                    // 1
  float* addv   = sumsq + 1;                  // 2*B*C = 1024

  hipMemsetAsync(d_ws, 0, (2 * Bc * Cc + Bc * Cc + 4 + 1) * sizeof(float),
                 stream);

  gc_fused<<<dim3(GRIDX, Bc), TPB, 0, stream>>>(S, T, wms, bms, wmt, bmt,
                                                ctxnum, rowsum, den, sumsq);
  gc_k4a_mlp<<<4, 1024, 0, stream>>>(ctxnum, den, w1s, b1s, gs, bes, w2s, b2s,
                                     w1t, b1t, gt, bet, w2t, b2t, addv);
  gc_k4b_final<<<1, 256, 0, stream>>>(addv, rowsum, sumsq, out);
}

// Round 8
// 218.077 us; speedup vs baseline: 1.0110x; 1.0110x over previous
//
#include <hip/hip_runtime.h>
#include <math.h>

// Problem constants (match reference: B,C,W,H,D = 2,256,32,32,32)
#define Bc   2
#define Cc   256
#define Nn   32768            // W*H*D
#define CHc  128              // C/2
#define LN_EPS 1e-5f

// gc_main tiling
#define TN    32              // spatial positions per tile
#define TPT   4               // tiles per block
#define TPB   256             // threads per block (4 waves)
#define NQ    8               // n-quads per tile (TN/4)
#define NB    (Nn / (TN * TPT))   // 256 blocks per b  -> grid (256, 2)
#define PR    772             // partial-row stride (cs256|ct256|rs256|denS|denT|sq|pad)

// Direct global->LDS DMA (16B/lane): zero VGPRs per outstanding load.
__device__ __forceinline__ void load_lds16(const float* g, float* l) {
  __builtin_amdgcn_global_load_lds(
      (const __attribute__((address_space(1))) void*)g,
      (__attribute__((address_space(3))) void*)l, 16, 0, 0);
}

// ---------------------------------------------------------------------------
// gc_main: ONE HBM pass. Per tile: stage 64 KB (2 x 256ch x 32n) into LDS via
// global_load_lds (wave-uniform dest + lane*16 scatter -> [c][n] layout),
// then mask -> exp (UNSHIFTED softmax: shift-invariant, |mask|<~2, fp32-exact,
// absmax 0.0 verified R4-R7) -> per-channel cs/ct/rs via 3-round 8-lane
// butterflies (thread tid owns channel tid). No global atomics: per-block
// partials stored coalesced to P[b][blk][772].
// ---------------------------------------------------------------------------
__global__ __launch_bounds__(TPB, 2) void gc_main(
    const float* __restrict__ S, const float* __restrict__ T,
    const float* __restrict__ wms, const float* __restrict__ bms,
    const float* __restrict__ wmt, const float* __restrict__ bmt,
    float* __restrict__ P) {
  const int b    = blockIdx.y;
  const int blk  = blockIdx.x;
  const int tid  = threadIdx.x;
  const int nq   = tid & (NQ - 1);
  const int cgrp = tid >> 3;          // 32 channel groups x 8 channels
  const int wv   = tid >> 6;          // 4 waves
  const int lane = tid & 63;
  const int c0   = cgrp * 8;

  __shared__ float  tileS[Cc * TN];   // 32 KB
  __shared__ float  tileT[Cc * TN];   // 32 KB
  __shared__ float4 mredw[2][4][NQ];  // 1 KB wave-level mask partials
  __shared__ float  sqred[4];

  const float bS = bms[0];
  const float bT = bmt[0];

  float wSv[8], wTv[8];
#pragma unroll
  for (int i = 0; i < 8; ++i) { wSv[i] = wms[c0 + i]; wTv[i] = wmt[c0 + i]; }

  float acc_cs = 0.f, acc_ct = 0.f, acc_rs = 0.f, acc_sq = 0.f;
  float acc_dens = 0.f, acc_dent = 0.f;

  const int r = lane >> 3, o = lane & 7;   // staging: row-in-group, 16B slot

  for (int it = 0; it < TPT; ++it) {
    const int n0 = (blk * TPT + it) * TN;

    // ---- stage: 16 lds-DMA wave-loads per wave (1 KB each), no VGPR use ----
#pragma unroll
    for (int j = 0; j < 16; ++j) {
      const int ttn = j >> 3;                  // tensor
      const int cb  = (wv * 8 + (j & 7)) * 8;  // 8-channel group base
      const float* gp = (ttn ? T : S) +
          ((size_t)(b * Cc + cb + r)) * Nn + n0 + o * 4;
      float* lp = (ttn ? tileT : tileS) + cb * TN;   // wave-uniform dest
      load_lds16(gp, lp);
    }
    __syncthreads();   // drains vmcnt (lds-DMA) + barrier

    const float4* tS4 = (const float4*)tileS;  // [c][nq] float4, stride 8
    const float4* tT4 = (const float4*)tileT;

    // ---- mask partials over this thread's 8 channels ----
    float4 ms = make_float4(0.f, 0.f, 0.f, 0.f);
    float4 mt = make_float4(0.f, 0.f, 0.f, 0.f);
#pragma unroll
    for (int i = 0; i < 8; ++i) {
      const float4 s = tS4[(c0 + i) * NQ + nq];
      const float4 t = tT4[(c0 + i) * NQ + nq];
      ms.x += wSv[i] * s.x; ms.y += wSv[i] * s.y;
      ms.z += wSv[i] * s.z; ms.w += wSv[i] * s.w;
      mt.x += wTv[i] * t.x; mt.y += wTv[i] * t.y;
      mt.z += wTv[i] * t.z; mt.w += wTv[i] * t.w;
    }
    // collapse the wave's 8 cgrp-subgroups (lane bits 3,4,5)
#pragma unroll
    for (int m = 8; m <= 32; m <<= 1) {
      ms.x += __shfl_xor(ms.x, m); ms.y += __shfl_xor(ms.y, m);
      ms.z += __shfl_xor(ms.z, m); ms.w += __shfl_xor(ms.w, m);
      mt.x += __shfl_xor(mt.x, m); mt.y += __shfl_xor(mt.y, m);
      mt.z += __shfl_xor(mt.z, m); mt.w += __shfl_xor(mt.w, m);
    }
    if (lane < NQ) { mredw[0][wv][nq] = ms; mredw[1][wv][nq] = mt; }
    __syncthreads();

    // ---- full mask across 4 waves, exp ----
    float4 Ms = make_float4(0.f, 0.f, 0.f, 0.f);
    float4 Mt = make_float4(0.f, 0.f, 0.f, 0.f);
#pragma unroll
    for (int w = 0; w < 4; ++w) {
      const float4 a = mredw[0][w][nq];
      Ms.x += a.x; Ms.y += a.y; Ms.z += a.z; Ms.w += a.w;
      const float4 c = mredw[1][w][nq];
      Mt.x += c.x; Mt.y += c.y; Mt.z += c.z; Mt.w += c.w;
    }
    float4 es, et;
    es.x = __expf(Ms.x + bS); es.y = __expf(Ms.y + bS);
    es.z = __expf(Ms.z + bS); es.w = __expf(Ms.w + bS);
    et.x = __expf(Mt.x + bT); et.y = __expf(Mt.y + bT);
    et.z = __expf(Mt.z + bT); et.w = __expf(Mt.w + bT);
    if (cgrp == 0) {   // lanes 0..7 of wave 0
      acc_dens += es.x + es.y + es.z + es.w;
      acc_dent += et.x + et.y + et.z + et.w;
    }

    // ---- per-channel cs/ct/rs: 3-round butterfly over the 8 nq lanes ----
#pragma unroll
    for (int i = 0; i < 8; ++i) {
      const float4 s = tS4[(c0 + i) * NQ + nq];
      const float4 t = tT4[(c0 + i) * NQ + nq];
      float cs = s.x * es.x + s.y * es.y + s.z * es.z + s.w * es.w;
      float ct = t.x * et.x + t.y * et.y + t.z * et.z + t.w * et.w;
      const float dx = s.x - t.x, dy = s.y - t.y;
      const float dz = s.z - t.z, dw = s.w - t.w;
      float rs = dx + dy + dz + dw;
      acc_sq += dx * dx + dy * dy + dz * dz + dw * dw;
#pragma unroll
      for (int m = 1; m <= 4; m <<= 1) {
        cs += __shfl_xor(cs, m);
        ct += __shfl_xor(ct, m);
        rs += __shfl_xor(rs, m);
      }
      if (nq == i) { acc_cs += cs; acc_ct += ct; acc_rs += rs; }
    }
    __syncthreads();   // WAR guard before next tile's staging
  }

  // ---- block epilogue ----
#pragma unroll
  for (int m = 1; m < 64; m <<= 1) acc_sq += __shfl_xor(acc_sq, m);
  if (lane == 0) sqred[wv] = acc_sq;
  if (wv == 0) {   // den partials live only in lanes 0..7 (zero elsewhere)
#pragma unroll
    for (int m = 1; m <= 4; m <<= 1) {
      acc_dens += __shfl_xor(acc_dens, m);
      acc_dent += __shfl_xor(acc_dent, m);
    }
  }
  __syncthreads();

  float* Prow = P + ((size_t)b * NB + blk) * PR;
  // thread tid owns channel tid (c = cgrp*8 + nq = tid)
  Prow[tid]       = acc_cs;
  Prow[Cc + tid]  = acc_ct;
  Prow[2 * Cc + tid] = acc_rs;
  if (tid == 0) {
    Prow[768] = acc_dens;
    Prow[769] = acc_dent;
    Prow[770] = sqred[0] + sqred[1] + sqred[2] + sqred[3];
  }
}

// ---------------------------------------------------------------------------
// gc_mlp: per (tt,b): reduce ctx/den partials over the 256 blocks, then the
// channel_add MLP (conv1 + LN + ReLU + conv2). grid 4, block 1024.
// ---------------------------------------------------------------------------
__global__ __launch_bounds__(1024) void gc_mlp(
    const float* __restrict__ P,
    const float* __restrict__ w1s, const float* __restrict__ b1s,
    const float* __restrict__ gs,  const float* __restrict__ bes,
    const float* __restrict__ w2s, const float* __restrict__ b2s,
    const float* __restrict__ w1t, const float* __restrict__ b1t,
    const float* __restrict__ gt,  const float* __restrict__ bet,
    const float* __restrict__ w2t, const float* __restrict__ b2t,
    float* __restrict__ addv) {
  const int tt  = blockIdx.x >> 1;
  const int b   = blockIdx.x & 1;
  const int tid = threadIdx.x;

  const float* w1 = tt ? w1t : w1s;
  const float* b1 = tt ? b1t : b1s;
  const float* g  = tt ? gt  : gs;
  const float* be = tt ? bet : bes;
  const float* w2 = tt ? w2t : w2s;
  const float* b2 = tt ? b2t : b2s;

  __shared__ float red4[4][Cc];
  __shared__ float den4[4];
  __shared__ float cxs[Cc];
  __shared__ float part[1024];
  __shared__ float hbuf[CHc];
  __shared__ float hr[CHc];
  __shared__ float2 red2[128];
  __shared__ float mu_s, rstd_s;

  // reduce ctx numerator + den over 256 blocks (4 groups of 64)
  {
    const int c = tid & (Cc - 1), gq = tid >> 8;
    float v = 0.f;
    for (int t = gq * 64; t < gq * 64 + 64; ++t)
      v += P[((size_t)b * NB + t) * PR + tt * Cc + c];
    red4[gq][c] = v;
    if (tid < 4) {
      float dv = 0.f;
      for (int t = tid * 64; t < tid * 64 + 64; ++t)
        dv += P[((size_t)b * NB + t) * PR + 768 + tt];
      den4[tid] = dv;
    }
  }
  __syncthreads();
  if (tid < Cc)
    cxs[tid] = (red4[0][tid] + red4[1][tid] + red4[2][tid] + red4[3][tid]) /
               (den4[0] + den4[1] + den4[2] + den4[3]);
  __syncthreads();

  // stage 1: h[j] = sum_c ctx[c]*w1[j][c] + b1[j]   (128 j x 8 segments)
  {
    const int j = tid >> 3, s = tid & 7;
    const float* wr = w1 + j * Cc + s * 32;
    const float4* cx4 = (const float4*)(cxs + s * 32);
    float acc = 0.f;
#pragma unroll
    for (int k = 0; k < 8; ++k) {
      const float4 w = *(const float4*)(wr + k * 4);
      const float4 x = cx4[k];
      acc += w.x * x.x + w.y * x.y + w.z * x.z + w.w * x.w;
    }
    part[tid] = acc;
  }
  __syncthreads();
  if (tid < CHc) {
    float h = b1[tid];
#pragma unroll
    for (int q = 0; q < 8; ++q) h += part[tid * 8 + q];
    hbuf[tid] = h;
  }
  __syncthreads();

  // LN stats over 128
  if (tid < CHc) {
    const float v = hbuf[tid];
    red2[tid] = make_float2(v, v * v);
  }
  __syncthreads();
  for (int s = 64; s > 0; s >>= 1) {
    if (tid < s) {
      red2[tid].x += red2[tid + s].x;
      red2[tid].y += red2[tid + s].y;
    }
    __syncthreads();
  }
  if (tid == 0) {
    const float mu = red2[0].x / (float)CHc;
    const float var = red2[0].y / (float)CHc - mu * mu;
    mu_s = mu;
    rstd_s = rsqrtf(var + LN_EPS);
  }
  __syncthreads();
  if (tid < CHc) {
    const float v = (hbuf[tid] - mu_s) * rstd_s * g[tid] + be[tid];
    hr[tid] = v > 0.f ? v : 0.f;
  }
  __syncthreads();

  // stage 3: addv[c] = sum_j hr[j]*w2[c][j] + b2[c]   (256 c x 4 segments)
  {
    const int c = tid >> 2, q = tid & 3;
    const float* wr = w2 + c * CHc + q * 32;
    const float4* h4 = (const float4*)(hr + q * 32);
    float acc = 0.f;
#pragma unroll
    for (int k = 0; k < 8; ++k) {
      const float4 w = *(const float4*)(wr + k * 4);
      const float4 x = h4[k];
      acc += w.x * x.x + w.y * x.y + w.z * x.z + w.w * x.w;
    }
    part[tid] = acc;
  }
  __syncthreads();
  if (tid < Cc) {
    float acc = b2[tid];
#pragma unroll
    for (int q = 0; q < 4; ++q) acc += part[tid * 4 + q];
    addv[((size_t)tt * Bc + b) * Cc + tid] = acc;
  }
}

// ---------------------------------------------------------------------------
// gc_fin: reduce rowsum + sq partials, then the closed-form final scalar.
// out = (sumsq + sum_{b,c} [2*delta*rowsum + N*delta^2]) / B.  1 block, 1024.
// ---------------------------------------------------------------------------
__global__ __launch_bounds__(1024) void gc_fin(
    const float* __restrict__ P, const float* __restrict__ addv,
    float* __restrict__ out) {
  const int tid = threadIdx.x;
  __shared__ float rs2[2][2][Cc];   // [half][b][c]
  __shared__ float red[1024];
  __shared__ float sq_tot;

  // rowsum partials: thread (h, b, c), halves of the 256 blocks
  {
    const int c = tid & (Cc - 1), b = (tid >> 8) & 1, h = tid >> 9;
    float v = 0.f;
    for (int t = h * 128; t < h * 128 + 128; ++t)
      v += P[((size_t)b * NB + t) * PR + 2 * Cc + c];
    rs2[h][b][c] = v;
  }
  // sq: 512 partials, tree-reduce
  {
    float sqv = 0.f;
    if (tid < 512) {
      const int b = tid >> 8, t = tid & (NB - 1);
      sqv = P[((size_t)b * NB + t) * PR + 770];
    }
    red[tid] = sqv;
  }
  __syncthreads();
  for (int s = 512; s > 0; s >>= 1) {
    if (tid < s) red[tid] += red[tid + s];
    __syncthreads();
  }
  if (tid == 0) sq_tot = red[0];
  __syncthreads();

  float part = 0.f;
  if (tid < Bc * Cc) {
    const int c = tid & (Cc - 1);
    const int b = tid >> 8;
    const float delta = addv[((size_t)0 * Bc + b) * Cc + c] -
                        addv[((size_t)1 * Bc + b) * Cc + c];
    const float rsum = rs2[0][b][c] + rs2[1][b][c];
    part = 2.f * delta * rsum + (float)Nn * delta * delta;
  }
  red[tid] = part;
  __syncthreads();
  for (int s = 512; s > 0; s >>= 1) {
    if (tid < s) red[tid] += red[tid + s];
    __syncthreads();
  }
  if (tid == 0) out[0] = (red[0] + sq_tot) / (float)Bc;
}

// ---------------------------------------------------------------------------
extern "C" void kernel_launch(void* const* d_in, const int* in_sizes, int n_in,
                              void* d_out, int out_size, void* d_ws,
                              size_t ws_size, hipStream_t stream) {
  const float* S   = (const float*)d_in[0];
  const float* T   = (const float*)d_in[1];
  const float* wms = (const float*)d_in[2];
  const float* bms = (const float*)d_in[3];
  const float* wmt = (const float*)d_in[4];
  const float* bmt = (const float*)d_in[5];
  const float* w1s = (const float*)d_in[6];
  const float* b1s = (const float*)d_in[7];
  const float* gs  = (const float*)d_in[8];
  const float* bes = (const float*)d_in[9];
  const float* w2s = (const float*)d_in[10];
  const float* b2s = (const float*)d_in[11];
  const float* w1t = (const float*)d_in[12];
  const float* b1t = (const float*)d_in[13];
  const float* gt  = (const float*)d_in[14];
  const float* bet = (const float*)d_in[15];
  const float* w2t = (const float*)d_in[16];
  const float* b2t = (const float*)d_in[17];
  float* out = (float*)d_out;

  // ws layout (floats). Everything written before read -> no memset needed.
  float* ws   = (float*)d_ws;
  float* P    = ws;                              // 2*NB*PR = 395,264 floats
  float* addv = P + (size_t)2 * NB * PR;         // 2*B*C = 1024

  gc_main<<<dim3(NB, Bc), TPB, 0, stream>>>(S, T, wms, bms, wmt, bmt, P);
  gc_mlp<<<4, 1024, 0, stream>>>(P, w1s, b1s, gs, bes, w2s, b2s,
                                 w1t, b1t, gt, bet, w2t, b2t, addv);
  gc_fin<<<1, 1024, 0, stream>>>(P, addv, out);
}